// Round 10
// baseline (121.943 us; speedup 1.0000x reference)
//
#include <hip/hip_runtime.h>
#include <hip/hip_bf16.h>

#define RADIUS_F 1.3f
#define NSAMP 767
#define STEPF 0.01015625f   // RADIUS*2/COARSE/FINE/2
#define BATCH 1024

typedef __attribute__((ext_vector_type(8))) short short8;
typedef __attribute__((ext_vector_type(4))) float floatx4;
typedef __fp16 fp16x2 __attribute__((ext_vector_type(2)));

static __device__ __forceinline__ unsigned pkbf(float a, float b) {
    union { __hip_bfloat162 h; unsigned u; } cvt;
    cvt.h = __float22bfloat162_rn(make_float2(a, b));
    return cvt.u;
}
static __device__ __forceinline__ unsigned pkh(float a, float b) {
    union { fp16x2 h; unsigned u; } c;
    c.h = __builtin_amdgcn_cvt_pkrtz(a, b);
    return c.u;
}
static __device__ __forceinline__ float2 uph(unsigned u) {
    union { unsigned u; fp16x2 h; } c; c.u = u;
    return make_float2((float)c.h.x, (float)c.h.y);
}
static __device__ __forceinline__ float bfhi(unsigned u) {   // expand bf16 bits (low 16) to f32
    union { unsigned u; float f; } c; c.u = u << 16; return c.f;
}

// sum over the 4-lane coset {i, i^4, i^8, i^12} inside each row of 16,
// via DPP row rotates (VALU pipe, no LDS)
static __device__ __forceinline__ float coset4_sum(float p) {
    int q4 = __builtin_amdgcn_update_dpp(0, __float_as_int(p), 0x124, 0xf, 0xf, true); // row_ror:4
    p = p + __int_as_float(q4);
    int q8 = __builtin_amdgcn_update_dpp(0, __float_as_int(p), 0x128, 0xf, 0xf, true); // row_ror:8
    return p + __int_as_float(q8);
}

// launch_bounds (512,8): 8 waves/EU -> 4 blocks/CU -> 32 waves/CU
__launch_bounds__(512, 8)
__global__ void plenoxels_fwd(const float* __restrict__ rays_o,
                              const float* __restrict__ rays_d,
                              const float* __restrict__ grid,
                              const float* __restrict__ atoms,
                              float* __restrict__ out)
{
    // LDS: 4096 (B'') + 15360 (Wp f16-pairs) + 1536 (alpha) + 4608 (rgb) + 192 = 25792 B
    __shared__ __align__(16) __hip_bfloat16 BpL[32 * 64];   // Bp[col][a], col = 4f+c
    __shared__ unsigned WpU[768 * 5];                       // (w[f],w[f+4]) f16x2, stride 5
    __shared__ __align__(4) __hip_bfloat16 alphaL[768];
    __shared__ __align__(4) __hip_bfloat16 rgbL[768 * 3];
    __shared__ float wprodL[8];
    __shared__ float partL[8][5];

    const int tid  = threadIdx.x;
    const int ray  = blockIdx.x;
    const int lane = tid & 63;
    const int w    = tid >> 6;        // 8 waves; wave owns samples [96w, 96w+96)
    const int m    = lane & 15;
    const int quad = lane >> 4;

    // ---- per-ray constants ----
    const float ox = rays_o[ray * 3 + 0], oy = rays_o[ray * 3 + 1], oz = rays_o[ray * 3 + 2];
    const float dx = rays_d[ray * 3 + 0], dy = rays_d[ray * 3 + 1], dz = rays_d[ray * 3 + 2];

    float start;
    {
        float a0 = (RADIUS_F - ox) / dx, b0 = (-RADIUS_F - ox) / dx;
        float a1 = (RADIUS_F - oy) / dy, b1 = (-RADIUS_F - oy) / dy;
        float a2 = (RADIUS_F - oz) / dz, b2 = (-RADIUS_F - oz) / dz;
        start = fmaxf(fminf(a0, b0), fmaxf(fminf(a1, b1), fminf(a2, b2)));
    }
    const float dnorm = sqrtf(dx * dx + dy * dy + dz * dz);
    const float dist = STEPF * dnorm;

    // geometry for one sample: writes packed W row (4 dwords) to LDS, returns clin
    auto geom = [&](int s) -> int {
        float tr = start + (float)s * STEPF;
        float px = ox + tr * dx, py = oy + tr * dy, pz = oz + tr * dz;
        int mask = (px > -RADIUS_F) & (px < RADIUS_F) &
                   (py > -RADIUS_F) & (py < RADIUS_F) &
                   (pz > -RADIUS_F) & (pz < RADIUS_F) & (s < NSAMP);
        float maskf = mask ? 1.f : 0.f;
        const float sc = 1.0f / (2.0f * RADIUS_F);
        float qx = fminf(fmaxf((px + RADIUS_F) * sc, 0.f), 1.0f - 1e-6f);
        float qy = fminf(fmaxf((py + RADIUS_F) * sc, 0.f), 1.0f - 1e-6f);
        float qz = fminf(fmaxf((pz + RADIUS_F) * sc, 0.f), 1.0f - 1e-6f);
        float pcx = qx * 64.f, pcy = qy * 64.f, pcz = qz * 64.f;
        float cx = fminf(floorf(pcx), 63.f);
        float cy = fminf(floorf(pcy), 63.f);
        float cz = fminf(floorf(pcz), 63.f);
        float lx = pcx - cx, ly = pcy - cy, lz = pcz - cz;
        int clin = (((int)cx * 64) + (int)cy) * 64 + (int)cz;
        float xw0, xw1, yw0, yw1, zw0, zw1;
        {
            float u = lx * 2.f - 0.5f, fF = floorf(u), t = u - fF;
            xw0 = (fF < 0.f) ? 1.f : ((fF > 0.f) ? 0.f : 1.f - t);
            xw1 = (fF < 0.f) ? 0.f : ((fF > 0.f) ? 1.f : t);
        }
        {
            float u = ly * 2.f - 0.5f, fF = floorf(u), t = u - fF;
            yw0 = (fF < 0.f) ? 1.f : ((fF > 0.f) ? 0.f : 1.f - t);
            yw1 = (fF < 0.f) ? 0.f : ((fF > 0.f) ? 1.f : t);
        }
        {
            float u = lz * 2.f - 0.5f, fF = floorf(u), t = u - fF;
            zw0 = (fF < 0.f) ? 1.f : ((fF > 0.f) ? 0.f : 1.f - t);
            zw1 = (fF < 0.f) ? 0.f : ((fF > 0.f) ? 1.f : t);
        }
        xw0 *= maskf; xw1 *= maskf;          // fold mask: W=0 => sigma=0, rgb pre-act=0
        float g0 = yw0 * zw0, g1 = yw0 * zw1, g2 = yw1 * zw0, g3 = yw1 * zw1;
        unsigned* wr = &WpU[s * 5];
        wr[0] = pkh(xw0 * g0, xw1 * g0);
        wr[1] = pkh(xw0 * g1, xw1 * g1);
        wr[2] = pkh(xw0 * g2, xw1 * g2);
        wr[3] = pkh(xw0 * g3, xw1 * g3);
        return clin;
    };

    // ---- wave-local geometry: pass A (64 samples) + pass B (32 samples) ----
    int clinA = geom(w * 96 + lane);
    int clinB = 0;
    if (lane < 32) clinB = geom(w * 96 + 64 + lane);

    // ---- tile-0 coeff gather issues now; latency hides under B'' build ----
    const float4* g4 = (const float4*)grid;
    float4 cv0, cv1, cv2, cv3;
    {
        int clinC = __shfl(clinA, m, 64);
        const float4* gp = g4 + (clinC << 4) + (quad << 2);
        cv0 = gp[0]; cv1 = gp[1]; cv2 = gp[2]; cv3 = gp[3];
    }

    // ---- build B''[a][col] (SH-contracted atoms), Bp[col][a], col = 4f+c ----
    {
        float shm[9];
        float inv = 1.0f / dnorm;
        float nx = dx * inv, ny = dy * inv, nz = dz * inv;
        shm[0] = 0.28209479177387814f;
        shm[1] = -0.4886025119029199f * ny;
        shm[2] = 0.4886025119029199f * nz;
        shm[3] = -0.4886025119029199f * nx;
        shm[4] = 1.0925484305920792f * nx * ny;
        shm[5] = -1.0925484305920792f * ny * nz;
        shm[6] = 0.31539156525252005f * (2.f * nz * nz - nx * nx - ny * ny);
        shm[7] = -1.0925484305920792f * nx * nz;
        shm[8] = 0.5462742152960396f * (nx * nx - ny * ny);
        for (int idx = tid; idx < 2048; idx += 512) {
            int col = idx >> 6, a = idx & 63;     // col uniform per wave per sweep
            int f = col >> 2, c = col & 3;
            const float* base = atoms + (f * 64 + a) * 28;
            float sv;
            if (c == 3) sv = base[27];
            else {
                sv = 0.f;
                #pragma unroll
                for (int i = 0; i < 9; ++i) sv = fmaf(base[c * 9 + i], shm[i], sv);
            }
            BpL[col * 64 + a] = __float2bfloat16(sv);
        }
    }
    __syncthreads();

    // ---- B-fragments (tile-invariant) ----
    short8 bq00, bq01, bq10, bq11;
    {
        const short* bs = (const short*)BpL;
        const short* p0 = bs + m * 64 + (quad << 4);
        bq00 = *(const short8*)(p0);
        bq01 = *(const short8*)(p0 + 8);
        const short* p1 = bs + (16 + m) * 64 + (quad << 4);
        bq10 = *(const short8*)(p1);
        bq11 = *(const short8*)(p1 + 8);
    }

    float* out_rgb   = out;
    float* out_alpha = out + BATCH * 3;
    float* out_depth = out + BATCH * 3 + BATCH * NSAMP;
    const int f0 = m >> 2;

    #pragma unroll
    for (int t = 0; t < 6; ++t) {
        // A-frags: raw coeff, bf16 (step ks uses a = 16*quad + ks)
        union { unsigned u[4]; short8 s; } a0, a1;
        a0.u[0] = pkbf(cv0.x, cv0.y); a0.u[1] = pkbf(cv0.z, cv0.w);
        a0.u[2] = pkbf(cv1.x, cv1.y); a0.u[3] = pkbf(cv1.z, cv1.w);
        a1.u[0] = pkbf(cv2.x, cv2.y); a1.u[1] = pkbf(cv2.z, cv2.w);
        a1.u[2] = pkbf(cv3.x, cv3.y); a1.u[3] = pkbf(cv3.z, cv3.w);

        // prefetch next tile's coeff gather (clin via shuffle, wave-local)
        if (t < 5) {
            int tn = t + 1;
            int clinC = (tn < 4) ? __shfl(clinA, (tn << 4) + m, 64)
                                 : __shfl(clinB, ((tn - 4) << 4) + m, 64);
            const float4* gp = g4 + (clinC << 4) + (quad << 2);
            cv0 = gp[0]; cv1 = gp[1]; cv2 = gp[2]; cv3 = gp[3];
        }

        // stage 1: proj = Coeff(16x64) x B''(64x32)
        floatx4 acc0 = {0.f, 0.f, 0.f, 0.f};
        floatx4 acc1 = {0.f, 0.f, 0.f, 0.f};
        acc0 = __builtin_amdgcn_mfma_f32_16x16x32_bf16(a0.s, bq00, acc0, 0, 0, 0);
        acc0 = __builtin_amdgcn_mfma_f32_16x16x32_bf16(a1.s, bq01, acc0, 0, 0, 0);
        acc1 = __builtin_amdgcn_mfma_f32_16x16x32_bf16(a0.s, bq10, acc1, 0, 0, 0);
        acc1 = __builtin_amdgcn_mfma_f32_16x16x32_bf16(a1.s, bq11, acc1, 0, 0, 0);

        // stage 2: out[s][c] = sum_f W[s][f] * proj[s][4f+c]
        #pragma unroll
        for (int r = 0; r < 4; ++r) {
            int s = w * 96 + (t << 4) + (quad << 2) + r;
            float2 wab = uph(WpU[s * 5 + f0]);        // one ds_read_b32 + 2 cvt
            float p = wab.x * acc0[r] + wab.y * acc1[r];
            p = coset4_sum(p);                        // reduce over f
            if (m == 3) {                             // sigma -> alpha
                float al = 1.f - __expf(-fmaxf(p, 0.f) * dist);
                if (s < NSAMP) out_alpha[ray * NSAMP + s] = al;  // exact fp32
                alphaL[s] = __float2bfloat16(al);     // pad s=767: mask=>al=0, safe
            } else if (m < 3) {                       // rgb channels
                rgbL[s * 3 + m] = __float2bfloat16(1.f / (1.f + __expf(-p)));
            }
        }
    }

    __syncthreads();

    // ---- phase 2: transmittance scan + composite, 6 waves x 2 samples/thread ----
    {
        const bool act = (tid < 384);
        const int s0 = tid * 2;            // 0..766 (act), pad pair otherwise
        float a0 = 0.f, a1 = 0.f;
        if (act) {
            unsigned aa = *(const unsigned*)&alphaL[s0];
            a0 = bfhi(aa & 0xffff);
            a1 = bfhi(aa >> 16);
        }
        float pr = (1.f - a0 + 1e-10f) * (1.f - a1 + 1e-10f);

        // intra-wave inclusive multiplicative scan over pair products
        float incl = pr;
        #pragma unroll
        for (int off = 1; off < 64; off <<= 1) {
            float v = __shfl_up(incl, off, 64);
            if (lane >= off) incl *= v;
        }
        if (lane == 63) wprodL[w] = incl;
        __syncthreads();

        float base = 1.f;
        #pragma unroll
        for (int ww = 0; ww < 5; ++ww)
            if (w > ww) base *= wprodL[ww];
        float excl = __shfl_up(incl, 1, 64);
        if (lane == 0) excl = 1.f;
        float trans = base * excl;

        float c0 = 0.f, c1 = 0.f, c2 = 0.f, accw = 0.f, dep = 0.f;
        if (act) {
            unsigned u01 = *(const unsigned*)&rgbL[s0 * 3];       // r0,g0
            unsigned u23 = *(const unsigned*)&rgbL[s0 * 3 + 2];   // b0,r1
            unsigned u45 = *(const unsigned*)&rgbL[s0 * 3 + 4];   // g1,b1
            float w0 = a0 * trans;
            c0 += w0 * bfhi(u01 & 0xffff);
            c1 += w0 * bfhi(u01 >> 16);
            c2 += w0 * bfhi(u23 & 0xffff);
            accw += w0;
            dep += w0 * (start + (float)s0 * STEPF);
            trans *= (1.f - a0 + 1e-10f);
            float w1 = a1 * trans;
            c0 += w1 * bfhi(u23 >> 16);
            c1 += w1 * bfhi(u45 & 0xffff);
            c2 += w1 * bfhi(u45 >> 16);
            accw += w1;
            dep += w1 * (start + (float)(s0 + 1) * STEPF);
        }
        #pragma unroll
        for (int off = 1; off < 64; off <<= 1) {
            c0   += __shfl_xor(c0, off, 64);
            c1   += __shfl_xor(c1, off, 64);
            c2   += __shfl_xor(c2, off, 64);
            accw += __shfl_xor(accw, off, 64);
            dep  += __shfl_xor(dep, off, 64);
        }
        if (lane == 0) {
            partL[w][0] = c0; partL[w][1] = c1; partL[w][2] = c2;
            partL[w][3] = accw; partL[w][4] = dep;
        }
        __syncthreads();
        if (tid == 0) {
            float C0 = 0.f, C1 = 0.f, C2 = 0.f, AC = 0.f, DP = 0.f;
            #pragma unroll
            for (int ww = 0; ww < 6; ++ww) {
                C0 += partL[ww][0]; C1 += partL[ww][1]; C2 += partL[ww][2];
                AC += partL[ww][3]; DP += partL[ww][4];
            }
            float bg = 1.f - AC;
            out_rgb[ray * 3 + 0] = C0 + bg;
            out_rgb[ray * 3 + 1] = C1 + bg;
            out_rgb[ray * 3 + 2] = C2 + bg;
            out_depth[ray] = DP;
        }
    }
}

extern "C" void kernel_launch(void* const* d_in, const int* in_sizes, int n_in,
                              void* d_out, int out_size, void* d_ws, size_t ws_size,
                              hipStream_t stream) {
    const float* rays_o = (const float*)d_in[0];
    const float* rays_d = (const float*)d_in[1];
    const float* grid   = (const float*)d_in[2];
    const float* atoms  = (const float*)d_in[3];
    float* out = (float*)d_out;
    hipLaunchKernelGGL(plenoxels_fwd, dim3(BATCH), dim3(512), 0, stream,
                       rays_o, rays_d, grid, atoms, out);
}

// Round 11
// 114.659 us; speedup vs baseline: 1.0635x; 1.0635x over previous
//
#include <hip/hip_runtime.h>
#include <hip/hip_bf16.h>

#define RADIUS_F 1.3f
#define NSAMP 767
#define STEPF 0.01015625f   // RADIUS*2/COARSE/FINE/2
#define BATCH 1024

typedef __attribute__((ext_vector_type(8))) short short8;
typedef __attribute__((ext_vector_type(4))) float floatx4;
typedef __fp16 fp16x2 __attribute__((ext_vector_type(2)));

static __device__ __forceinline__ unsigned pkbf(float a, float b) {
    union { __hip_bfloat162 h; unsigned u; } cvt;
    cvt.h = __float22bfloat162_rn(make_float2(a, b));
    return cvt.u;
}
static __device__ __forceinline__ unsigned pkh(float a, float b) {
    union { fp16x2 h; unsigned u; } c;
    c.h = __builtin_amdgcn_cvt_pkrtz(a, b);
    return c.u;
}
static __device__ __forceinline__ float2 uph(unsigned u) {
    union { unsigned u; fp16x2 h; } c; c.u = u;
    return make_float2((float)c.h.x, (float)c.h.y);
}
static __device__ __forceinline__ float bfx(unsigned short u) {  // bf16 bits -> f32
    union { unsigned u; float f; } c; c.u = ((unsigned)u) << 16; return c.f;
}

// sum over the 4-lane coset {i, i^4, i^8, i^12} inside each row of 16,
// via DPP row rotates (VALU pipe, no LDS)
static __device__ __forceinline__ float coset4_sum(float p) {
    int q4 = __builtin_amdgcn_update_dpp(0, __float_as_int(p), 0x124, 0xf, 0xf, true); // row_ror:4
    p = p + __int_as_float(q4);
    int q8 = __builtin_amdgcn_update_dpp(0, __float_as_int(p), 0x128, 0xf, 0xf, true); // row_ror:8
    return p + __int_as_float(q8);
}

// launch_bounds (512,8): 8 waves/EU -> 4 blocks/CU -> 32 waves/CU
__launch_bounds__(512, 8)
__global__ void plenoxels_fwd(const float* __restrict__ rays_o,
                              const float* __restrict__ rays_d,
                              const float* __restrict__ grid,
                              const float* __restrict__ atoms,
                              float* __restrict__ out)
{
    // LDS: 4096 (B'') + 15360 (Wp) + 6144 (pL) + 192 = 25792 B
    __shared__ __align__(16) __hip_bfloat16 BpL[32 * 64];   // Bp[col][a], col = 4f+c
    __shared__ unsigned WpU[768 * 5];                       // (w[f],w[f+4]) f16x2, stride 5
    __shared__ __align__(16) __hip_bfloat16 pL[768 * 4];    // raw pre-activation p[s][c]
    __shared__ float wprodL[8];
    __shared__ float partL[8][5];

    const int tid  = threadIdx.x;
    const int ray  = blockIdx.x;
    const int lane = tid & 63;
    const int w    = tid >> 6;        // 8 waves; wave owns samples [96w, 96w+96)
    const int m    = lane & 15;
    const int quad = lane >> 4;

    // ---- per-ray constants ----
    const float ox = rays_o[ray * 3 + 0], oy = rays_o[ray * 3 + 1], oz = rays_o[ray * 3 + 2];
    const float dx = rays_d[ray * 3 + 0], dy = rays_d[ray * 3 + 1], dz = rays_d[ray * 3 + 2];

    float start;
    {
        float a0 = (RADIUS_F - ox) / dx, b0 = (-RADIUS_F - ox) / dx;
        float a1 = (RADIUS_F - oy) / dy, b1 = (-RADIUS_F - oy) / dy;
        float a2 = (RADIUS_F - oz) / dz, b2 = (-RADIUS_F - oz) / dz;
        start = fmaxf(fminf(a0, b0), fmaxf(fminf(a1, b1), fminf(a2, b2)));
    }
    const float dnorm = sqrtf(dx * dx + dy * dy + dz * dz);
    const float dist = STEPF * dnorm;

    // geometry for one sample: writes packed W row (4 dwords) to LDS, returns clin
    auto geom = [&](int s) -> int {
        float tr = start + (float)s * STEPF;
        float px = ox + tr * dx, py = oy + tr * dy, pz = oz + tr * dz;
        int mask = (px > -RADIUS_F) & (px < RADIUS_F) &
                   (py > -RADIUS_F) & (py < RADIUS_F) &
                   (pz > -RADIUS_F) & (pz < RADIUS_F) & (s < NSAMP);
        float maskf = mask ? 1.f : 0.f;
        const float sc = 1.0f / (2.0f * RADIUS_F);
        float qx = fminf(fmaxf((px + RADIUS_F) * sc, 0.f), 1.0f - 1e-6f);
        float qy = fminf(fmaxf((py + RADIUS_F) * sc, 0.f), 1.0f - 1e-6f);
        float qz = fminf(fmaxf((pz + RADIUS_F) * sc, 0.f), 1.0f - 1e-6f);
        float pcx = qx * 64.f, pcy = qy * 64.f, pcz = qz * 64.f;
        float cx = fminf(floorf(pcx), 63.f);
        float cy = fminf(floorf(pcy), 63.f);
        float cz = fminf(floorf(pcz), 63.f);
        float lx = pcx - cx, ly = pcy - cy, lz = pcz - cz;
        int clin = (((int)cx * 64) + (int)cy) * 64 + (int)cz;
        float xw0, xw1, yw0, yw1, zw0, zw1;
        {
            float u = lx * 2.f - 0.5f, fF = floorf(u), t = u - fF;
            xw0 = (fF < 0.f) ? 1.f : ((fF > 0.f) ? 0.f : 1.f - t);
            xw1 = (fF < 0.f) ? 0.f : ((fF > 0.f) ? 1.f : t);
        }
        {
            float u = ly * 2.f - 0.5f, fF = floorf(u), t = u - fF;
            yw0 = (fF < 0.f) ? 1.f : ((fF > 0.f) ? 0.f : 1.f - t);
            yw1 = (fF < 0.f) ? 0.f : ((fF > 0.f) ? 1.f : t);
        }
        {
            float u = lz * 2.f - 0.5f, fF = floorf(u), t = u - fF;
            zw0 = (fF < 0.f) ? 1.f : ((fF > 0.f) ? 0.f : 1.f - t);
            zw1 = (fF < 0.f) ? 0.f : ((fF > 0.f) ? 1.f : t);
        }
        xw0 *= maskf; xw1 *= maskf;          // fold mask: W=0 => sigma=0, rgb pre-act=0
        float g0 = yw0 * zw0, g1 = yw0 * zw1, g2 = yw1 * zw0, g3 = yw1 * zw1;
        unsigned* wr = &WpU[s * 5];
        wr[0] = pkh(xw0 * g0, xw1 * g0);
        wr[1] = pkh(xw0 * g1, xw1 * g1);
        wr[2] = pkh(xw0 * g2, xw1 * g2);
        wr[3] = pkh(xw0 * g3, xw1 * g3);
        return clin;
    };

    // ---- wave-local geometry: pass A (64 samples) + pass B (32 samples) ----
    int clinA = geom(w * 96 + lane);
    int clinB = 0;
    if (lane < 32) clinB = geom(w * 96 + 64 + lane);

    // ---- tile-0 coeff gather issues now; latency hides under B'' build ----
    const float4* g4 = (const float4*)grid;
    float4 cv0, cv1, cv2, cv3;
    {
        int clinC = __shfl(clinA, m, 64);
        const float4* gp = g4 + (clinC << 4) + (quad << 2);
        cv0 = gp[0]; cv1 = gp[1]; cv2 = gp[2]; cv3 = gp[3];
    }

    // ---- build B'': one (f,a) entry per thread, contiguous 112 B atoms row ----
    // entry fa = tid: f = tid>>6, a = tid&63; cols 4f+c, c<3 SH-contracted, c=3 sigma
    {
        float shm[9];
        float inv = 1.0f / dnorm;
        float nx = dx * inv, ny = dy * inv, nz = dz * inv;
        shm[0] = 0.28209479177387814f;
        shm[1] = -0.4886025119029199f * ny;
        shm[2] = 0.4886025119029199f * nz;
        shm[3] = -0.4886025119029199f * nx;
        shm[4] = 1.0925484305920792f * nx * ny;
        shm[5] = -1.0925484305920792f * ny * nz;
        shm[6] = 0.31539156525252005f * (2.f * nz * nz - nx * nx - ny * ny);
        shm[7] = -1.0925484305920792f * nx * nz;
        shm[8] = 0.5462742152960396f * (nx * nx - ny * ny);

        const float* base = atoms + tid * 28;
        float4 v0 = *(const float4*)(base);
        float4 v1 = *(const float4*)(base + 4);
        float4 v2 = *(const float4*)(base + 8);
        float4 v3 = *(const float4*)(base + 12);
        float4 v4 = *(const float4*)(base + 16);
        float4 v5 = *(const float4*)(base + 20);
        float4 v6 = *(const float4*)(base + 24);

        float s0 = v0.x*shm[0] + v0.y*shm[1] + v0.z*shm[2] + v0.w*shm[3]
                 + v1.x*shm[4] + v1.y*shm[5] + v1.z*shm[6] + v1.w*shm[7] + v2.x*shm[8];
        float s1 = v2.y*shm[0] + v2.z*shm[1] + v2.w*shm[2] + v3.x*shm[3]
                 + v3.y*shm[4] + v3.z*shm[5] + v3.w*shm[6] + v4.x*shm[7] + v4.y*shm[8];
        float s2 = v4.z*shm[0] + v4.w*shm[1] + v5.x*shm[2] + v5.y*shm[3]
                 + v5.z*shm[4] + v5.w*shm[5] + v6.x*shm[6] + v6.y*shm[7] + v6.z*shm[8];

        int f = tid >> 6, a = tid & 63;
        int cb = (f << 2) << 6;              // (4f)*64
        BpL[cb + a]        = __float2bfloat16(s0);
        BpL[cb + 64 + a]   = __float2bfloat16(s1);
        BpL[cb + 128 + a]  = __float2bfloat16(s2);
        BpL[cb + 192 + a]  = __float2bfloat16(v6.w);   // sigma column
    }
    __syncthreads();

    // ---- B-fragments (tile-invariant) ----
    short8 bq00, bq01, bq10, bq11;
    {
        const short* bs = (const short*)BpL;
        const short* p0 = bs + m * 64 + (quad << 4);
        bq00 = *(const short8*)(p0);
        bq01 = *(const short8*)(p0 + 8);
        const short* p1 = bs + (16 + m) * 64 + (quad << 4);
        bq10 = *(const short8*)(p1);
        bq11 = *(const short8*)(p1 + 8);
    }

    float* out_rgb   = out;
    float* out_alpha = out + BATCH * 3;
    float* out_depth = out + BATCH * 3 + BATCH * NSAMP;
    const int f0 = m >> 2;

    #pragma unroll
    for (int t = 0; t < 6; ++t) {
        // A-frags: raw coeff, bf16 (step ks uses a = 16*quad + ks)
        union { unsigned u[4]; short8 s; } a0, a1;
        a0.u[0] = pkbf(cv0.x, cv0.y); a0.u[1] = pkbf(cv0.z, cv0.w);
        a0.u[2] = pkbf(cv1.x, cv1.y); a0.u[3] = pkbf(cv1.z, cv1.w);
        a1.u[0] = pkbf(cv2.x, cv2.y); a1.u[1] = pkbf(cv2.z, cv2.w);
        a1.u[2] = pkbf(cv3.x, cv3.y); a1.u[3] = pkbf(cv3.z, cv3.w);

        // prefetch next tile's coeff gather (clin via shuffle, wave-local)
        if (t < 5) {
            int tn = t + 1;
            int clinC = (tn < 4) ? __shfl(clinA, (tn << 4) + m, 64)
                                 : __shfl(clinB, ((tn - 4) << 4) + m, 64);
            const float4* gp = g4 + (clinC << 4) + (quad << 2);
            cv0 = gp[0]; cv1 = gp[1]; cv2 = gp[2]; cv3 = gp[3];
        }

        // stage 1: proj = Coeff(16x64) x B''(64x32)
        floatx4 acc0 = {0.f, 0.f, 0.f, 0.f};
        floatx4 acc1 = {0.f, 0.f, 0.f, 0.f};
        acc0 = __builtin_amdgcn_mfma_f32_16x16x32_bf16(a0.s, bq00, acc0, 0, 0, 0);
        acc0 = __builtin_amdgcn_mfma_f32_16x16x32_bf16(a1.s, bq01, acc0, 0, 0, 0);
        acc1 = __builtin_amdgcn_mfma_f32_16x16x32_bf16(a0.s, bq10, acc1, 0, 0, 0);
        acc1 = __builtin_amdgcn_mfma_f32_16x16x32_bf16(a1.s, bq11, acc1, 0, 0, 0);

        // stage 2: p[s][c] = sum_f W[s][f]*proj[s][4f+c]; write RAW p, no transcendentals
        #pragma unroll
        for (int r = 0; r < 4; ++r) {
            int s = w * 96 + (t << 4) + (quad << 2) + r;
            float2 wab = uph(WpU[s * 5 + f0]);        // one ds_read_b32 + 2 cvt
            float p = wab.x * acc0[r] + wab.y * acc1[r];
            p = coset4_sum(p);                        // reduce over f
            if (m < 4) pL[(s << 2) + m] = __float2bfloat16(p);
        }
    }

    __syncthreads();

    // ---- phase 2: activations + transmittance scan + composite (full lanes) ----
    {
        const bool act = (tid < 384);
        const int s0 = tid * 2;            // 0..766 (act)
        float a0 = 0.f, a1 = 0.f;
        float r0 = 0.f, g0 = 0.f, b0 = 0.f, r1 = 0.f, g1 = 0.f, b1 = 0.f;
        if (act) {
            short8 pv = *(const short8*)&pL[s0 << 2];  // one ds_read_b128: 2 samples x 4 ch
            a0 = 1.f - __expf(-fmaxf(bfx((unsigned short)pv[3]), 0.f) * dist);
            a1 = 1.f - __expf(-fmaxf(bfx((unsigned short)pv[7]), 0.f) * dist);
            r0 = 1.f / (1.f + __expf(-bfx((unsigned short)pv[0])));
            g0 = 1.f / (1.f + __expf(-bfx((unsigned short)pv[1])));
            b0 = 1.f / (1.f + __expf(-bfx((unsigned short)pv[2])));
            r1 = 1.f / (1.f + __expf(-bfx((unsigned short)pv[4])));
            g1 = 1.f / (1.f + __expf(-bfx((unsigned short)pv[5])));
            b1 = 1.f / (1.f + __expf(-bfx((unsigned short)pv[6])));
            // coalesced alpha store (consecutive threads -> consecutive dwords)
            out_alpha[ray * NSAMP + s0] = a0;
            if (s0 + 1 < NSAMP) out_alpha[ray * NSAMP + s0 + 1] = a1;
        }
        float pr = (1.f - a0 + 1e-10f) * (1.f - a1 + 1e-10f);

        // intra-wave inclusive multiplicative scan over pair products
        float incl = pr;
        #pragma unroll
        for (int off = 1; off < 64; off <<= 1) {
            float v = __shfl_up(incl, off, 64);
            if (lane >= off) incl *= v;
        }
        if (lane == 63) wprodL[w] = incl;
        __syncthreads();

        float base = 1.f;
        #pragma unroll
        for (int ww = 0; ww < 5; ++ww)
            if (w > ww) base *= wprodL[ww];
        float excl = __shfl_up(incl, 1, 64);
        if (lane == 0) excl = 1.f;
        float trans = base * excl;

        float c0 = 0.f, c1 = 0.f, c2 = 0.f, accw = 0.f, dep = 0.f;
        if (act) {
            float w0 = a0 * trans;
            c0 += w0 * r0; c1 += w0 * g0; c2 += w0 * b0;
            accw += w0;
            dep += w0 * (start + (float)s0 * STEPF);
            trans *= (1.f - a0 + 1e-10f);
            float w1 = a1 * trans;
            c0 += w1 * r1; c1 += w1 * g1; c2 += w1 * b1;
            accw += w1;
            dep += w1 * (start + (float)(s0 + 1) * STEPF);
        }
        #pragma unroll
        for (int off = 1; off < 64; off <<= 1) {
            c0   += __shfl_xor(c0, off, 64);
            c1   += __shfl_xor(c1, off, 64);
            c2   += __shfl_xor(c2, off, 64);
            accw += __shfl_xor(accw, off, 64);
            dep  += __shfl_xor(dep, off, 64);
        }
        if (lane == 0) {
            partL[w][0] = c0; partL[w][1] = c1; partL[w][2] = c2;
            partL[w][3] = accw; partL[w][4] = dep;
        }
        __syncthreads();
        if (tid == 0) {
            float C0 = 0.f, C1 = 0.f, C2 = 0.f, AC = 0.f, DP = 0.f;
            #pragma unroll
            for (int ww = 0; ww < 6; ++ww) {
                C0 += partL[ww][0]; C1 += partL[ww][1]; C2 += partL[ww][2];
                AC += partL[ww][3]; DP += partL[ww][4];
            }
            float bg = 1.f - AC;
            out_rgb[ray * 3 + 0] = C0 + bg;
            out_rgb[ray * 3 + 1] = C1 + bg;
            out_rgb[ray * 3 + 2] = C2 + bg;
            out_depth[ray] = DP;
        }
    }
}

extern "C" void kernel_launch(void* const* d_in, const int* in_sizes, int n_in,
                              void* d_out, int out_size, void* d_ws, size_t ws_size,
                              hipStream_t stream) {
    const float* rays_o = (const float*)d_in[0];
    const float* rays_d = (const float*)d_in[1];
    const float* grid   = (const float*)d_in[2];
    const float* atoms  = (const float*)d_in[3];
    float* out = (float*)d_out;
    hipLaunchKernelGGL(plenoxels_fwd, dim3(BATCH), dim3(512), 0, stream,
                       rays_o, rays_d, grid, atoms, out);
}